// Round 6
// baseline (433.395 us; speedup 1.0000x reference)
//
#include <hip/hip_runtime.h>
#include <math.h>

#define NEG 0.2f
#define CHUNK 16384

__device__ __forceinline__ float lrelu(float v) { return fmaxf(v, NEG * v); }

__device__ __forceinline__ unsigned short f2bf(float f) {
    unsigned u = __float_as_uint(f);
    u = (u + 0x7fffu + ((u >> 16) & 1u)) >> 16;   // RNE
    return (unsigned short)u;
}
__device__ __forceinline__ float bf2f(unsigned short s) {
    return __uint_as_float((unsigned)s << 16);
}

// K1: h1 = x@W1 -> bf16, plus fp32-exact attention logits. (proven R4/R5)
__global__ __launch_bounds__(256) void k1(const float* __restrict__ x,
        const float* __restrict__ W1, const float* __restrict__ a_src,
        const float* __restrict__ a_dst,
        unsigned short* __restrict__ h1b, float* __restrict__ als,
        float* __restrict__ ald, int N)
{
    __shared__ float Wl[128 * 64];
    __shared__ float xt[128][68];

    const int tid = threadIdx.x;
    const int base = blockIdx.x * 64;

    const float4* Wv = (const float4*)W1;
    float4* Wlv = (float4*)Wl;
    for (int i = tid; i < 128 * 16; i += 256) Wlv[i] = Wv[i];

    for (int idx = tid; idx < 64 * 32; idx += 256) {
        int nl = idx >> 5;
        int k4 = (idx & 31) * 4;
        int n = base + nl;
        float4 v = make_float4(0.f, 0.f, 0.f, 0.f);
        if (n < N) v = *(const float4*)&x[(size_t)n * 128 + k4];
        xt[k4 + 0][nl] = v.x;
        xt[k4 + 1][nl] = v.y;
        xt[k4 + 2][nl] = v.z;
        xt[k4 + 3][nl] = v.w;
    }
    __syncthreads();

    const int wave = tid >> 6, lane = tid & 63;
    const int g = lane >> 4, c = lane & 15;
    const int nl0 = wave * 16 + 4 * g;

    float acc[4][4];
    #pragma unroll
    for (int j = 0; j < 4; ++j)
        #pragma unroll
        for (int t = 0; t < 4; ++t) acc[j][t] = 0.f;

    #pragma unroll 4
    for (int k = 0; k < 128; ++k) {
        float4 wv = *(const float4*)&Wl[k * 64 + 4 * c];
        float4 xv = *(const float4*)&xt[k][nl0];
        const float xs[4] = {xv.x, xv.y, xv.z, xv.w};
        const float wsv[4] = {wv.x, wv.y, wv.z, wv.w};
        #pragma unroll
        for (int j = 0; j < 4; ++j)
            #pragma unroll
            for (int t = 0; t < 4; ++t)
                acc[j][t] = fmaf(xs[j], wsv[t], acc[j][t]);
    }

    float a_s[4], a_d[4];
    #pragma unroll
    for (int t = 0; t < 4; ++t) { a_s[t] = a_src[4 * c + t]; a_d[t] = a_dst[4 * c + t]; }

    #pragma unroll
    for (int j = 0; j < 4; ++j) {
        int n = base + nl0 + j;
        float ps = 0.f, pd = 0.f;
        #pragma unroll
        for (int t = 0; t < 4; ++t) {
            ps = fmaf(acc[j][t], a_s[t], ps);
            pd = fmaf(acc[j][t], a_d[t], pd);
        }
        ps += __shfl_xor(ps, 1, 64);
        pd += __shfl_xor(pd, 1, 64);
        if (n < N) {
            ushort4 hb;
            hb.x = f2bf(acc[j][0]); hb.y = f2bf(acc[j][1]);
            hb.z = f2bf(acc[j][2]); hb.w = f2bf(acc[j][3]);
            *(ushort4*)&h1b[(size_t)n * 64 + 4 * c] = hb;
            if ((c & 1) == 0) {
                als[n * 8 + (c >> 1)] = ps;
                ald[n * 8 + (c >> 1)] = pd;
            }
        }
    }
}

// ---------- atomic-free CSR build (P1..P4, proven R5) ----------

__global__ __launch_bounds__(256) void p1(const int* __restrict__ ei, int E, int N,
        int* __restrict__ T, int NB, int NC)
{
    extern __shared__ int hist[];
    int tid = threadIdx.x;
    for (int b = tid; b < NB; b += 256) hist[b] = 0;
    __syncthreads();
    int base = blockIdx.x * CHUNK;
    for (int i = tid; i < CHUNK; i += 256) {
        int e = base + i;
        if (e >= E) break;
        int d = ei[E + e];
        if ((unsigned)d < (unsigned)N) atomicAdd(&hist[d >> 8], 1);
    }
    __syncthreads();
    for (int b = tid; b < NB; b += 256) T[b * NC + blockIdx.x] = hist[b];
}

__global__ __launch_bounds__(256) void p2a(int* __restrict__ T,
        int* __restrict__ total, int NB, int NC)
{
    int wave = threadIdx.x >> 6, lane = threadIdx.x & 63;
    int b = blockIdx.x * 4 + wave;
    if (b >= NB) return;
    int run = 0;
    for (int j0 = 0; j0 < NC; j0 += 64) {
        int j = j0 + lane;
        int orig = (j < NC) ? T[b * NC + j] : 0;
        int v = orig;
        #pragma unroll
        for (int off = 1; off < 64; off <<= 1) {
            int t = __shfl_up(v, off, 64);
            if (lane >= off) v += t;
        }
        if (j < NC) T[b * NC + j] = run + v - orig;
        run += __shfl(v, 63, 64);
    }
    if (lane == 0) total[b] = run;
}

__global__ __launch_bounds__(512) void p2b(const int* __restrict__ total,
        int* __restrict__ bstart, int nb)
{
    __shared__ int s[512];
    int tid = threadIdx.x;
    int run = 0;
    for (int base = 0; base < nb; base += 512) {
        int i = base + tid;
        int orig = (i < nb) ? total[i] : 0;
        s[tid] = orig;
        __syncthreads();
        #pragma unroll
        for (int off = 1; off < 512; off <<= 1) {
            int t = (tid >= off) ? s[tid - off] : 0;
            __syncthreads();
            s[tid] += t;
            __syncthreads();
        }
        if (i < nb) bstart[i] = run + s[tid] - orig;
        int tot = s[511];
        __syncthreads();
        run += tot;
    }
    if (tid == 0) bstart[nb] = run;
}

__global__ __launch_bounds__(256) void p3(const int* __restrict__ ei, int E, int N,
        const int* __restrict__ T, const int* __restrict__ bstart,
        unsigned* __restrict__ tmp, int NB, int NC)
{
    extern __shared__ int cur[];
    int tid = threadIdx.x;
    int j = blockIdx.x;
    for (int b = tid; b < NB; b += 256) cur[b] = bstart[b] + T[b * NC + j];
    __syncthreads();
    int base = j * CHUNK;
    for (int i = tid; i < CHUNK; i += 256) {
        int e = base + i;
        if (e >= E) break;
        int d = ei[E + e];
        if ((unsigned)d >= (unsigned)N) continue;
        int s = ei[e];
        if ((unsigned)s >= (unsigned)N) s = 0;
        int pos = atomicAdd(&cur[d >> 8], 1);
        if ((unsigned)pos < (unsigned)E)
            tmp[pos] = (unsigned)s | ((unsigned)(d & 255) << 24);
    }
}

__global__ __launch_bounds__(256) void p4(const unsigned* __restrict__ tmp,
        const int* __restrict__ bstart,
        int* __restrict__ cnt, int* __restrict__ rowptr, int* __restrict__ csr,
        int N, int E)
{
    __shared__ int hist[256];
    __shared__ int ssc[256];
    __shared__ int cur[256];
    int tid = threadIdx.x;
    int b = blockIdx.x;
    int s0 = bstart[b], s1 = bstart[b + 1];
    if (s0 < 0) s0 = 0; if (s0 > E) s0 = E;
    if (s1 < s0) s1 = s0; if (s1 > E) s1 = E;

    hist[tid] = 0;
    __syncthreads();
    for (int i = s0 + tid; i < s1; i += 256)
        atomicAdd(&hist[tmp[i] >> 24], 1);
    __syncthreads();

    int h = hist[tid];
    ssc[tid] = h;
    __syncthreads();
    #pragma unroll
    for (int off = 1; off < 256; off <<= 1) {
        int t = (tid >= off) ? ssc[tid - off] : 0;
        __syncthreads();
        ssc[tid] += t;
        __syncthreads();
    }
    int excl = ssc[tid] - h;
    int node = b * 256 + tid;
    if (node < N) {
        cnt[node] = h;
        rowptr[node] = s0 + excl;
    }
    cur[tid] = s0 + excl;
    __syncthreads();

    for (int i = s0 + tid; i < s1; i += 256) {
        unsigned v = tmp[i];
        int pos = atomicAdd(&cur[v >> 24], 1);
        if ((unsigned)pos < (unsigned)E) csr[pos] = (int)(v & 0xFFFFFFu);
    }
}

// ---------- fallback atomic build (proven R3/R4) ----------

__global__ __launch_bounds__(256) void kh(const int* __restrict__ ei, int E, int N,
                                          int* __restrict__ cnt)
{
    int e = blockIdx.x * 256 + threadIdx.x;
    if (e >= E) return;
    int d = ei[E + e];
    if ((unsigned)d < (unsigned)N) atomicAdd(&cnt[d], 1);
}

__global__ __launch_bounds__(256) void ka(const int* __restrict__ cnt,
        int* __restrict__ rowptr, int* __restrict__ cursor,
        int* __restrict__ gtotal, int N)
{
    __shared__ int s[256];
    __shared__ int base;
    int tid = threadIdx.x;
    int g = blockIdx.x * 256 + tid;
    int v = (g < N) ? cnt[g] : 0;
    s[tid] = v;
    __syncthreads();
    #pragma unroll
    for (int off = 1; off < 256; off <<= 1) {
        int t = (tid >= off) ? s[tid - off] : 0;
        __syncthreads();
        s[tid] += t;
        __syncthreads();
    }
    if (tid == 255) base = atomicAdd(gtotal, s[255]);
    __syncthreads();
    if (g < N) {
        int r = base + s[tid] - v;
        rowptr[g] = r;
        cursor[g] = r;
    }
}

__global__ __launch_bounds__(256) void kc(const int* __restrict__ ei, int E, int N,
        int* __restrict__ cursor, int* __restrict__ csr)
{
    int e = blockIdx.x * 256 + threadIdx.x;
    if (e >= E) return;
    int s = ei[e];
    int d = ei[E + e];
    if ((unsigned)d >= (unsigned)N) return;
    int p = atomicAdd(&cursor[d], 1);
    if ((unsigned)p < (unsigned)E) csr[p] = s;
}

// ---------- G1 v3: dedup-exp + paired-col gather ----------
// One wave per dst node. Two lane mappings:
//  weight phase: lane = (e&7)*8 + h  -> computes w(edge,head) ONCE (coalesced
//                32B als reads), accumulates partial denominator.
//  fma phase:    lane = s*32 + cp (s = edge parity, cp = col pair); per 2
//                edges one dword load (2 bf16 cols); w and src<<5 offsets
//                fetched from weight lanes via constant-index bpermute.
__global__ __launch_bounds__(256) void g1(const int* __restrict__ csr,
        const int* __restrict__ rowptr, const int* __restrict__ cnt,
        const unsigned short* __restrict__ h1b, const float* __restrict__ als,
        const float* __restrict__ ald,
        const float* __restrict__ b1, const float* __restrict__ W2,
        const float* __restrict__ a_src2, const float* __restrict__ a_dst2,
        float2* __restrict__ h2a, float* __restrict__ ald2, int N, int E)
{
    const int wave = threadIdx.x >> 6, lane = threadIdx.x & 63;
    const int n = blockIdx.x * 4 + wave;
    if (n >= N) return;

    const int s = lane >> 5;          // edge parity for fma phase
    const int cp = lane & 31;         // col pair: cols 2cp, 2cp+1
    const int hp = cp >> 2;           // head of this col pair
    const int eslot = lane >> 3;      // weight phase: edge slot 0..7
    const int hw = lane & 7;          // weight phase: head

    const unsigned* h1w = (const unsigned*)h1b;   // dword view: [node*32 + cp]

    const float ald_hw = ald[n * 8 + hw];
    float denp = 0.f;
    float acc0 = 0.f, acc1 = 0.f;

    int start = rowptr[n];
    int c = cnt[n];
    if ((unsigned)start >= (unsigned)E) { start = 0; c = 0; }
    if (c < 0) c = 0;
    if (start + c > E) c = E - start;

    // constant bpermute indices per round: weight lane (el*8 + hp), el = 2r+s
    int wi0 = (2 * 0 + s) * 8 + hp;
    int wi1 = (2 * 1 + s) * 8 + hp;
    int wi2 = (2 * 2 + s) * 8 + hp;
    int wi3 = (2 * 3 + s) * 8 + hp;

    for (int cbase = 0; cbase < c; cbase += 64) {
        int rem = c - cbase; if (rem > 64) rem = 64;
        int sv = 0;
        if (lane < rem) {
            int t = csr[start + cbase + lane];
            if ((unsigned)t < (unsigned)N) sv = t;
        }
        for (int g0 = 0; g0 < rem; g0 += 8) {
            // ---- weight phase: edge g0+eslot, head hw ----
            int ge = g0 + eslot;                       // < 64 always
            int esrc = __shfl(sv, ge, 64);
            float wv = 0.f;
            if (ge < rem)
                wv = __expf(lrelu(als[esrc * 8 + hw] + ald_hw));
            denp += wv;
            int eoff = esrc << 5;                      // dword row offset

            // ---- fma phase: rounds of 2 edges (parity s) ----
            int nr = rem - g0; if (nr > 8) nr = 8;
            #pragma unroll
            for (int r = 0; r < 4; ++r) {
                if (2 * r >= nr) break;                // uniform
                int wi = (r == 0) ? wi0 : (r == 1) ? wi1 : (r == 2) ? wi2 : wi3;
                float fw = __shfl(wv, wi, 64);         // 0 for invalid edge
                int fo = __shfl(eoff, wi, 64);
                unsigned u = h1w[fo + cp];
                acc0 = fmaf(fw, __uint_as_float(u << 16), acc0);
                acc1 = fmaf(fw, __uint_as_float(u & 0xffff0000u), acc1);
            }
        }
    }

    // denominator: reduce partials over edge-slot bits (3,4,5)
    float dsum = denp;
    dsum += __shfl_xor(dsum, 8, 64);
    dsum += __shfl_xor(dsum, 16, 64);
    dsum += __shfl_xor(dsum, 32, 64);
    float den = __shfl(dsum, hp, 64);       // edges-only denom for this head

    // combine the two edge-parity halves
    acc0 += __shfl_xor(acc0, 32, 64);
    acc1 += __shfl_xor(acc1, 32, 64);

    // self-loop
    float wsf = __expf(lrelu(als[n * 8 + hp] + ald[n * 8 + hp]));
    unsigned un = h1w[(n << 5) + cp];
    den += wsf;
    acc0 = fmaf(wsf, __uint_as_float(un << 16), acc0);
    acc1 = fmaf(wsf, __uint_as_float(un & 0xffff0000u), acc1);

    // epilogue: normalize, +b1, ReLU, dot W2, reduce within 32-lane half
    float2 bb = *(const float2*)&b1[2 * cp];
    float2 w2 = *(const float2*)&W2[2 * cp];
    float v0 = fmaxf(acc0 / den + bb.x, 0.f);
    float v1 = fmaxf(acc1 / den + bb.y, 0.f);
    float t = fmaf(v0, w2.x, v1 * w2.y);
    #pragma unroll
    for (int off = 1; off < 32; off <<= 1) t += __shfl_xor(t, off, 64);
    if (lane == 0) {
        float2 p;
        p.x = t;
        p.y = t * a_src2[0];
        h2a[n] = p;
        ald2[n] = t * a_dst2[0];
    }
}

// G2: fused layer-2 gather + final normalize (proven R4/R5).
__global__ __launch_bounds__(256) void g2(const int* __restrict__ csr,
        const int* __restrict__ rowptr, const int* __restrict__ cnt,
        const float2* __restrict__ h2a, const float* __restrict__ ald2,
        const float* __restrict__ b2, float* __restrict__ out, int N, int E)
{
    int sub = threadIdx.x >> 5;
    int l32 = threadIdx.x & 31;
    int n = blockIdx.x * 8 + sub;
    if (n >= N) return;

    float ad = ald2[n];
    int start = rowptr[n];
    int c = cnt[n];
    if ((unsigned)start >= (unsigned)E) { start = 0; c = 0; }
    if (c < 0) c = 0;
    if (start + c > E) c = E - start;

    float den = 0.f, acc = 0.f;
    for (int i = l32; i < c; i += 32) {
        int src = csr[start + i];
        if ((unsigned)src >= (unsigned)N) src = 0;
        float2 p = h2a[src];
        float w = __expf(lrelu(p.y + ad));
        den += w;
        acc = fmaf(w, p.x, acc);
    }
    #pragma unroll
    for (int off = 1; off < 32; off <<= 1) {
        den += __shfl_xor(den, off, 32);
        acc += __shfl_xor(acc, off, 32);
    }
    if (l32 == 0) {
        float2 p = h2a[n];
        float w0 = __expf(lrelu(p.y + ad));
        out[n] = (acc + w0 * p.x) / (den + w0) + b2[0];
    }
}

extern "C" void kernel_launch(void* const* d_in, const int* in_sizes, int n_in,
                              void* d_out, int out_size, void* d_ws, size_t ws_size,
                              hipStream_t stream)
{
    const float* x   = (const float*)d_in[0];
    const float* W1  = (const float*)d_in[1];
    const float* as1 = (const float*)d_in[2];
    const float* ad1 = (const float*)d_in[3];
    const float* b1  = (const float*)d_in[4];
    const float* W2  = (const float*)d_in[5];
    const float* as2 = (const float*)d_in[6];
    const float* ad2 = (const float*)d_in[7];
    const float* b2  = (const float*)d_in[8];
    const int*   ei  = (const int*)d_in[9];

    int N = in_sizes[0] / 128;
    int E = in_sizes[9] / 2;
    int NB = (N + 255) >> 8;
    int NC = (E + CHUNK - 1) / CHUNK;

    char* wsb = (char*)d_ws;
    size_t off = 0;
    auto alloc = [&](size_t bytes) -> char* {
        char* p = wsb + off;
        off = (off + bytes + 255) & ~(size_t)255;
        return p;
    };

    unsigned short* h1b = (unsigned short*)alloc((size_t)N * 64 * 2);
    float* als    = (float*)alloc((size_t)N * 8 * 4);
    float* ald    = (float*)alloc((size_t)N * 8 * 4);
    float2* h2a   = (float2*)alloc((size_t)N * 8);
    float* ald2   = (float*)alloc((size_t)N * 4);
    int* cnt      = (int*)alloc((size_t)N * 4);
    int* rowptr   = (int*)alloc((size_t)N * 4);
    int* csr      = (int*)alloc((size_t)E * 4);
    size_t common = off;

    int* T        = (int*)alloc((size_t)NB * NC * 4);
    int* total    = (int*)alloc((size_t)NB * 4);
    int* bstart   = (int*)alloc((size_t)(NB + 1) * 4);
    unsigned* tmp = (unsigned*)alloc((size_t)E * 4);
    size_t need_new = off;

    k1<<<(N + 63) / 64, 256, 0, stream>>>(x, W1, as1, ad1, h1b, als, ald, N);

    if (ws_size >= need_new && NB <= 512) {
        size_t lds = (size_t)NB * 4;
        p1<<<NC, 256, lds, stream>>>(ei, E, N, T, NB, NC);
        p2a<<<(NB + 3) / 4, 256, 0, stream>>>(T, total, NB, NC);
        p2b<<<1, 512, 0, stream>>>(total, bstart, NB);
        p3<<<NC, 256, lds, stream>>>(ei, E, N, T, bstart, tmp, NB, NC);
        p4<<<NB, 256, 0, stream>>>(tmp, bstart, cnt, rowptr, csr, N, E);
    } else {
        off = common;
        int* gtotal = (int*)alloc(32);
        int* cursor = (int*)alloc((size_t)N * 4);
        hipMemsetAsync(cnt, 0, (size_t)N * sizeof(int), stream);
        hipMemsetAsync(gtotal, 0, 32, stream);
        kh<<<(E + 255) / 256, 256, 0, stream>>>(ei, E, N, cnt);
        ka<<<(N + 255) / 256, 256, 0, stream>>>(cnt, rowptr, cursor, gtotal, N);
        kc<<<(E + 255) / 256, 256, 0, stream>>>(ei, E, N, cursor, csr);
    }

    g1<<<(N + 3) / 4, 256, 0, stream>>>(csr, rowptr, cnt, h1b, als, ald,
                                        b1, W2, as2, ad2, h2a, ald2, N, E);
    g2<<<(N + 7) / 8, 256, 0, stream>>>(csr, rowptr, cnt, h2a, ald2, b2,
                                        (float*)d_out, N, E);
}

// Round 7
// 416.343 us; speedup vs baseline: 1.0410x; 1.0410x over previous
//
#include <hip/hip_runtime.h>
#include <math.h>

#define NEG 0.2f
#define CHUNK 16384

__device__ __forceinline__ float lrelu(float v) { return fmaxf(v, NEG * v); }

__device__ __forceinline__ unsigned short f2bf(float f) {
    unsigned u = __float_as_uint(f);
    u = (u + 0x7fffu + ((u >> 16) & 1u)) >> 16;   // RNE
    return (unsigned short)u;
}
__device__ __forceinline__ float bf2f(unsigned short s) {
    return __uint_as_float((unsigned)s << 16);
}

// K1: h1 = x@W1 -> bf16, plus fp32-exact attention logits. (proven R4/R5)
__global__ __launch_bounds__(256) void k1(const float* __restrict__ x,
        const float* __restrict__ W1, const float* __restrict__ a_src,
        const float* __restrict__ a_dst,
        unsigned short* __restrict__ h1b, float* __restrict__ als,
        float* __restrict__ ald, int N)
{
    __shared__ float Wl[128 * 64];
    __shared__ float xt[128][68];

    const int tid = threadIdx.x;
    const int base = blockIdx.x * 64;

    const float4* Wv = (const float4*)W1;
    float4* Wlv = (float4*)Wl;
    for (int i = tid; i < 128 * 16; i += 256) Wlv[i] = Wv[i];

    for (int idx = tid; idx < 64 * 32; idx += 256) {
        int nl = idx >> 5;
        int k4 = (idx & 31) * 4;
        int n = base + nl;
        float4 v = make_float4(0.f, 0.f, 0.f, 0.f);
        if (n < N) v = *(const float4*)&x[(size_t)n * 128 + k4];
        xt[k4 + 0][nl] = v.x;
        xt[k4 + 1][nl] = v.y;
        xt[k4 + 2][nl] = v.z;
        xt[k4 + 3][nl] = v.w;
    }
    __syncthreads();

    const int wave = tid >> 6, lane = tid & 63;
    const int g = lane >> 4, c = lane & 15;
    const int nl0 = wave * 16 + 4 * g;

    float acc[4][4];
    #pragma unroll
    for (int j = 0; j < 4; ++j)
        #pragma unroll
        for (int t = 0; t < 4; ++t) acc[j][t] = 0.f;

    #pragma unroll 4
    for (int k = 0; k < 128; ++k) {
        float4 wv = *(const float4*)&Wl[k * 64 + 4 * c];
        float4 xv = *(const float4*)&xt[k][nl0];
        const float xs[4] = {xv.x, xv.y, xv.z, xv.w};
        const float wsv[4] = {wv.x, wv.y, wv.z, wv.w};
        #pragma unroll
        for (int j = 0; j < 4; ++j)
            #pragma unroll
            for (int t = 0; t < 4; ++t)
                acc[j][t] = fmaf(xs[j], wsv[t], acc[j][t]);
    }

    float a_s[4], a_d[4];
    #pragma unroll
    for (int t = 0; t < 4; ++t) { a_s[t] = a_src[4 * c + t]; a_d[t] = a_dst[4 * c + t]; }

    #pragma unroll
    for (int j = 0; j < 4; ++j) {
        int n = base + nl0 + j;
        float ps = 0.f, pd = 0.f;
        #pragma unroll
        for (int t = 0; t < 4; ++t) {
            ps = fmaf(acc[j][t], a_s[t], ps);
            pd = fmaf(acc[j][t], a_d[t], pd);
        }
        ps += __shfl_xor(ps, 1, 64);
        pd += __shfl_xor(pd, 1, 64);
        if (n < N) {
            ushort4 hb;
            hb.x = f2bf(acc[j][0]); hb.y = f2bf(acc[j][1]);
            hb.z = f2bf(acc[j][2]); hb.w = f2bf(acc[j][3]);
            *(ushort4*)&h1b[(size_t)n * 64 + 4 * c] = hb;
            if ((c & 1) == 0) {
                als[n * 8 + (c >> 1)] = ps;
                ald[n * 8 + (c >> 1)] = pd;
            }
        }
    }
}

// ---------- atomic-free CSR build (P1..P4, proven R5) ----------

__global__ __launch_bounds__(256) void p1(const int* __restrict__ ei, int E, int N,
        int* __restrict__ T, int NB, int NC)
{
    extern __shared__ int hist[];
    int tid = threadIdx.x;
    for (int b = tid; b < NB; b += 256) hist[b] = 0;
    __syncthreads();
    int base = blockIdx.x * CHUNK;
    for (int i = tid; i < CHUNK; i += 256) {
        int e = base + i;
        if (e >= E) break;
        int d = ei[E + e];
        if ((unsigned)d < (unsigned)N) atomicAdd(&hist[d >> 8], 1);
    }
    __syncthreads();
    for (int b = tid; b < NB; b += 256) T[b * NC + blockIdx.x] = hist[b];
}

__global__ __launch_bounds__(256) void p2a(int* __restrict__ T,
        int* __restrict__ total, int NB, int NC)
{
    int wave = threadIdx.x >> 6, lane = threadIdx.x & 63;
    int b = blockIdx.x * 4 + wave;
    if (b >= NB) return;
    int run = 0;
    for (int j0 = 0; j0 < NC; j0 += 64) {
        int j = j0 + lane;
        int orig = (j < NC) ? T[b * NC + j] : 0;
        int v = orig;
        #pragma unroll
        for (int off = 1; off < 64; off <<= 1) {
            int t = __shfl_up(v, off, 64);
            if (lane >= off) v += t;
        }
        if (j < NC) T[b * NC + j] = run + v - orig;
        run += __shfl(v, 63, 64);
    }
    if (lane == 0) total[b] = run;
}

__global__ __launch_bounds__(512) void p2b(const int* __restrict__ total,
        int* __restrict__ bstart, int nb)
{
    __shared__ int s[512];
    int tid = threadIdx.x;
    int run = 0;
    for (int base = 0; base < nb; base += 512) {
        int i = base + tid;
        int orig = (i < nb) ? total[i] : 0;
        s[tid] = orig;
        __syncthreads();
        #pragma unroll
        for (int off = 1; off < 512; off <<= 1) {
            int t = (tid >= off) ? s[tid - off] : 0;
            __syncthreads();
            s[tid] += t;
            __syncthreads();
        }
        if (i < nb) bstart[i] = run + s[tid] - orig;
        int tot = s[511];
        __syncthreads();
        run += tot;
    }
    if (tid == 0) bstart[nb] = run;
}

__global__ __launch_bounds__(256) void p3(const int* __restrict__ ei, int E, int N,
        const int* __restrict__ T, const int* __restrict__ bstart,
        unsigned* __restrict__ tmp, int NB, int NC)
{
    extern __shared__ int cur[];
    int tid = threadIdx.x;
    int j = blockIdx.x;
    for (int b = tid; b < NB; b += 256) cur[b] = bstart[b] + T[b * NC + j];
    __syncthreads();
    int base = j * CHUNK;
    for (int i = tid; i < CHUNK; i += 256) {
        int e = base + i;
        if (e >= E) break;
        int d = ei[E + e];
        if ((unsigned)d >= (unsigned)N) continue;
        int s = ei[e];
        if ((unsigned)s >= (unsigned)N) s = 0;
        int pos = atomicAdd(&cur[d >> 8], 1);
        if ((unsigned)pos < (unsigned)E)
            tmp[pos] = (unsigned)s | ((unsigned)(d & 255) << 24);
    }
}

__global__ __launch_bounds__(256) void p4(const unsigned* __restrict__ tmp,
        const int* __restrict__ bstart,
        int* __restrict__ cnt, int* __restrict__ rowptr, int* __restrict__ csr,
        int N, int E)
{
    __shared__ int hist[256];
    __shared__ int ssc[256];
    __shared__ int cur[256];
    int tid = threadIdx.x;
    int b = blockIdx.x;
    int s0 = bstart[b], s1 = bstart[b + 1];
    if (s0 < 0) s0 = 0; if (s0 > E) s0 = E;
    if (s1 < s0) s1 = s0; if (s1 > E) s1 = E;

    hist[tid] = 0;
    __syncthreads();
    for (int i = s0 + tid; i < s1; i += 256)
        atomicAdd(&hist[tmp[i] >> 24], 1);
    __syncthreads();

    int h = hist[tid];
    ssc[tid] = h;
    __syncthreads();
    #pragma unroll
    for (int off = 1; off < 256; off <<= 1) {
        int t = (tid >= off) ? ssc[tid - off] : 0;
        __syncthreads();
        ssc[tid] += t;
        __syncthreads();
    }
    int excl = ssc[tid] - h;
    int node = b * 256 + tid;
    if (node < N) {
        cnt[node] = h;
        rowptr[node] = s0 + excl;
    }
    cur[tid] = s0 + excl;
    __syncthreads();

    for (int i = s0 + tid; i < s1; i += 256) {
        unsigned v = tmp[i];
        int pos = atomicAdd(&cur[v >> 24], 1);
        if ((unsigned)pos < (unsigned)E) csr[pos] = (int)(v & 0xFFFFFFu);
    }
}

// ---------- fallback atomic build (proven R3/R4) ----------

__global__ __launch_bounds__(256) void kh(const int* __restrict__ ei, int E, int N,
                                          int* __restrict__ cnt)
{
    int e = blockIdx.x * 256 + threadIdx.x;
    if (e >= E) return;
    int d = ei[E + e];
    if ((unsigned)d < (unsigned)N) atomicAdd(&cnt[d], 1);
}

__global__ __launch_bounds__(256) void ka(const int* __restrict__ cnt,
        int* __restrict__ rowptr, int* __restrict__ cursor,
        int* __restrict__ gtotal, int N)
{
    __shared__ int s[256];
    __shared__ int base;
    int tid = threadIdx.x;
    int g = blockIdx.x * 256 + tid;
    int v = (g < N) ? cnt[g] : 0;
    s[tid] = v;
    __syncthreads();
    #pragma unroll
    for (int off = 1; off < 256; off <<= 1) {
        int t = (tid >= off) ? s[tid - off] : 0;
        __syncthreads();
        s[tid] += t;
        __syncthreads();
    }
    if (tid == 255) base = atomicAdd(gtotal, s[255]);
    __syncthreads();
    if (g < N) {
        int r = base + s[tid] - v;
        rowptr[g] = r;
        cursor[g] = r;
    }
}

__global__ __launch_bounds__(256) void kc(const int* __restrict__ ei, int E, int N,
        int* __restrict__ cursor, int* __restrict__ csr)
{
    int e = blockIdx.x * 256 + threadIdx.x;
    if (e >= E) return;
    int s = ei[e];
    int d = ei[E + e];
    if ((unsigned)d >= (unsigned)N) return;
    int p = atomicAdd(&cursor[d], 1);
    if ((unsigned)p < (unsigned)E) csr[p] = s;
}

// ---------- G1 v4: parity-split dword gather, no inner-loop weight shuffles ----------
// One wave per dst node. s = lane>>5 selects edge parity; cp = lane&31 is the
// col pair (2 bf16 per dword load); hp = cp>>2 is this lane's head. Each half
// processes one edge per step: lane computes its head's exp itself (4-way
// duplicated — cheap) so the only cross-lane op in the loop is the sv shuffle,
// keeping load addresses shallow (MLP preserved; unroll 4 => 8 loads in flight).
__global__ __launch_bounds__(256) void g1(const int* __restrict__ csr,
        const int* __restrict__ rowptr, const int* __restrict__ cnt,
        const unsigned short* __restrict__ h1b, const float* __restrict__ als,
        const float* __restrict__ ald,
        const float* __restrict__ b1, const float* __restrict__ W2,
        const float* __restrict__ a_src2, const float* __restrict__ a_dst2,
        float2* __restrict__ h2a, float* __restrict__ ald2, int N, int E)
{
    const int wave = threadIdx.x >> 6, lane = threadIdx.x & 63;
    const int n = blockIdx.x * 4 + wave;
    if (n >= N) return;

    const int s = lane >> 5;          // edge parity
    const int cp = lane & 31;         // col pair: cols 2cp, 2cp+1
    const int hp = cp >> 2;           // head of this col pair

    const unsigned* h1w = (const unsigned*)h1b;   // dword view: [node*32 + cp]

    const float ald_hp = ald[n * 8 + hp];
    float denp = 0.f;                 // edges of parity s (identical across the
                                      // 4 cp-lanes of a head — no cp reduction)
    float acc0 = 0.f, acc1 = 0.f;

    int start = rowptr[n];
    int c = cnt[n];
    if ((unsigned)start >= (unsigned)E) { start = 0; c = 0; }
    if (c < 0) c = 0;
    if (start + c > E) c = E - start;

    for (int cbase = 0; cbase < c; cbase += 64) {
        int rem = c - cbase; if (rem > 64) rem = 64;
        int sv = 0;
        if (lane < rem) {
            int t = csr[start + cbase + lane];
            if ((unsigned)t < (unsigned)N) sv = t;
        }
        int steps = (rem + 1) >> 1;
        #pragma unroll 4
        for (int i = 0; i < steps; ++i) {
            int ge = 2 * i + s;                      // edge slot in chunk (<64)
            int esrc = __shfl(sv, ge, 64);           // 0 if ge >= rem (safe addr)
            float w = __expf(lrelu(als[esrc * 8 + hp] + ald_hp));
            if (ge >= rem) w = 0.f;
            denp += w;
            unsigned u = h1w[(esrc << 5) + cp];
            acc0 = fmaf(w, __uint_as_float(u << 16), acc0);
            acc1 = fmaf(w, __uint_as_float(u & 0xffff0000u), acc1);
        }
    }

    // combine the two edge-parity halves
    float den = denp + __shfl_xor(denp, 32, 64);
    acc0 += __shfl_xor(acc0, 32, 64);
    acc1 += __shfl_xor(acc1, 32, 64);

    // self-loop (after combine — added once per lane, consistent across lanes)
    float wsf = __expf(lrelu(als[n * 8 + hp] + ald_hp));
    unsigned un = h1w[(n << 5) + cp];
    den += wsf;
    acc0 = fmaf(wsf, __uint_as_float(un << 16), acc0);
    acc1 = fmaf(wsf, __uint_as_float(un & 0xffff0000u), acc1);

    // epilogue: normalize, +b1, ReLU, dot W2, reduce within 32-lane half
    float2 bb = *(const float2*)&b1[2 * cp];
    float2 w2 = *(const float2*)&W2[2 * cp];
    float v0 = fmaxf(acc0 / den + bb.x, 0.f);
    float v1 = fmaxf(acc1 / den + bb.y, 0.f);
    float t = fmaf(v0, w2.x, v1 * w2.y);
    #pragma unroll
    for (int off = 1; off < 32; off <<= 1) t += __shfl_xor(t, off, 64);
    if (lane == 0) {
        float2 p;
        p.x = t;
        p.y = t * a_src2[0];
        h2a[n] = p;
        ald2[n] = t * a_dst2[0];
    }
}

// G2: fused layer-2 gather + final normalize (proven R4/R5).
__global__ __launch_bounds__(256) void g2(const int* __restrict__ csr,
        const int* __restrict__ rowptr, const int* __restrict__ cnt,
        const float2* __restrict__ h2a, const float* __restrict__ ald2,
        const float* __restrict__ b2, float* __restrict__ out, int N, int E)
{
    int sub = threadIdx.x >> 5;
    int l32 = threadIdx.x & 31;
    int n = blockIdx.x * 8 + sub;
    if (n >= N) return;

    float ad = ald2[n];
    int start = rowptr[n];
    int c = cnt[n];
    if ((unsigned)start >= (unsigned)E) { start = 0; c = 0; }
    if (c < 0) c = 0;
    if (start + c > E) c = E - start;

    float den = 0.f, acc = 0.f;
    for (int i = l32; i < c; i += 32) {
        int src = csr[start + i];
        if ((unsigned)src >= (unsigned)N) src = 0;
        float2 p = h2a[src];
        float w = __expf(lrelu(p.y + ad));
        den += w;
        acc = fmaf(w, p.x, acc);
    }
    #pragma unroll
    for (int off = 1; off < 32; off <<= 1) {
        den += __shfl_xor(den, off, 32);
        acc += __shfl_xor(acc, off, 32);
    }
    if (l32 == 0) {
        float2 p = h2a[n];
        float w0 = __expf(lrelu(p.y + ad));
        out[n] = (acc + w0 * p.x) / (den + w0) + b2[0];
    }
}

extern "C" void kernel_launch(void* const* d_in, const int* in_sizes, int n_in,
                              void* d_out, int out_size, void* d_ws, size_t ws_size,
                              hipStream_t stream)
{
    const float* x   = (const float*)d_in[0];
    const float* W1  = (const float*)d_in[1];
    const float* as1 = (const float*)d_in[2];
    const float* ad1 = (const float*)d_in[3];
    const float* b1  = (const float*)d_in[4];
    const float* W2  = (const float*)d_in[5];
    const float* as2 = (const float*)d_in[6];
    const float* ad2 = (const float*)d_in[7];
    const float* b2  = (const float*)d_in[8];
    const int*   ei  = (const int*)d_in[9];

    int N = in_sizes[0] / 128;
    int E = in_sizes[9] / 2;
    int NB = (N + 255) >> 8;
    int NC = (E + CHUNK - 1) / CHUNK;

    char* wsb = (char*)d_ws;
    size_t off = 0;
    auto alloc = [&](size_t bytes) -> char* {
        char* p = wsb + off;
        off = (off + bytes + 255) & ~(size_t)255;
        return p;
    };

    unsigned short* h1b = (unsigned short*)alloc((size_t)N * 64 * 2);
    float* als    = (float*)alloc((size_t)N * 8 * 4);
    float* ald    = (float*)alloc((size_t)N * 8 * 4);
    float2* h2a   = (float2*)alloc((size_t)N * 8);
    float* ald2   = (float*)alloc((size_t)N * 4);
    int* cnt      = (int*)alloc((size_t)N * 4);
    int* rowptr   = (int*)alloc((size_t)N * 4);
    int* csr      = (int*)alloc((size_t)E * 4);
    size_t common = off;

    int* T        = (int*)alloc((size_t)NB * NC * 4);
    int* total    = (int*)alloc((size_t)NB * 4);
    int* bstart   = (int*)alloc((size_t)(NB + 1) * 4);
    unsigned* tmp = (unsigned*)alloc((size_t)E * 4);
    size_t need_new = off;

    k1<<<(N + 63) / 64, 256, 0, stream>>>(x, W1, as1, ad1, h1b, als, ald, N);

    if (ws_size >= need_new && NB <= 512) {
        size_t lds = (size_t)NB * 4;
        p1<<<NC, 256, lds, stream>>>(ei, E, N, T, NB, NC);
        p2a<<<(NB + 3) / 4, 256, 0, stream>>>(T, total, NB, NC);
        p2b<<<1, 512, 0, stream>>>(total, bstart, NB);
        p3<<<NC, 256, lds, stream>>>(ei, E, N, T, bstart, tmp, NB, NC);
        p4<<<NB, 256, 0, stream>>>(tmp, bstart, cnt, rowptr, csr, N, E);
    } else {
        off = common;
        int* gtotal = (int*)alloc(32);
        int* cursor = (int*)alloc((size_t)N * 4);
        hipMemsetAsync(cnt, 0, (size_t)N * sizeof(int), stream);
        hipMemsetAsync(gtotal, 0, 32, stream);
        kh<<<(E + 255) / 256, 256, 0, stream>>>(ei, E, N, cnt);
        ka<<<(N + 255) / 256, 256, 0, stream>>>(cnt, rowptr, cursor, gtotal, N);
        kc<<<(E + 255) / 256, 256, 0, stream>>>(ei, E, N, cursor, csr);
    }

    g1<<<(N + 3) / 4, 256, 0, stream>>>(csr, rowptr, cnt, h1b, als, ald,
                                        b1, W2, as2, ad2, h2a, ald2, N, E);
    g2<<<(N + 7) / 8, 256, 0, stream>>>(csr, rowptr, cnt, h2a, ald2, b2,
                                        (float*)d_out, N, E);
}

// Round 9
// 387.306 us; speedup vs baseline: 1.1190x; 1.0750x over previous
//
#include <hip/hip_runtime.h>
#include <math.h>

#define NEG 0.2f
#define CHUNK 16384

__device__ __forceinline__ float lrelu(float v) { return fmaxf(v, NEG * v); }

__device__ __forceinline__ unsigned short f2bf(float f) {
    unsigned u = __float_as_uint(f);
    u = (u + 0x7fffu + ((u >> 16) & 1u)) >> 16;   // RNE
    return (unsigned short)u;
}

// K1: h1 = x@W1 -> bf16, plus fp32-exact attention logits. (proven R4-R7)
__global__ __launch_bounds__(256) void k1(const float* __restrict__ x,
        const float* __restrict__ W1, const float* __restrict__ a_src,
        const float* __restrict__ a_dst,
        unsigned short* __restrict__ h1b, float* __restrict__ als,
        float* __restrict__ ald, int N)
{
    __shared__ float Wl[128 * 64];
    __shared__ float xt[128][68];

    const int tid = threadIdx.x;
    const int base = blockIdx.x * 64;

    const float4* Wv = (const float4*)W1;
    float4* Wlv = (float4*)Wl;
    for (int i = tid; i < 128 * 16; i += 256) Wlv[i] = Wv[i];

    for (int idx = tid; idx < 64 * 32; idx += 256) {
        int nl = idx >> 5;
        int k4 = (idx & 31) * 4;
        int n = base + nl;
        float4 v = make_float4(0.f, 0.f, 0.f, 0.f);
        if (n < N) v = *(const float4*)&x[(size_t)n * 128 + k4];
        xt[k4 + 0][nl] = v.x;
        xt[k4 + 1][nl] = v.y;
        xt[k4 + 2][nl] = v.z;
        xt[k4 + 3][nl] = v.w;
    }
    __syncthreads();

    const int wave = tid >> 6, lane = tid & 63;
    const int g = lane >> 4, c = lane & 15;
    const int nl0 = wave * 16 + 4 * g;

    float acc[4][4];
    #pragma unroll
    for (int j = 0; j < 4; ++j)
        #pragma unroll
        for (int t = 0; t < 4; ++t) acc[j][t] = 0.f;

    #pragma unroll 4
    for (int k = 0; k < 128; ++k) {
        float4 wv = *(const float4*)&Wl[k * 64 + 4 * c];
        float4 xv = *(const float4*)&xt[k][nl0];
        const float xs[4] = {xv.x, xv.y, xv.z, xv.w};
        const float wsv[4] = {wv.x, wv.y, wv.z, wv.w};
        #pragma unroll
        for (int j = 0; j < 4; ++j)
            #pragma unroll
            for (int t = 0; t < 4; ++t)
                acc[j][t] = fmaf(xs[j], wsv[t], acc[j][t]);
    }

    float a_s[4], a_d[4];
    #pragma unroll
    for (int t = 0; t < 4; ++t) { a_s[t] = a_src[4 * c + t]; a_d[t] = a_dst[4 * c + t]; }

    #pragma unroll
    for (int j = 0; j < 4; ++j) {
        int n = base + nl0 + j;
        float ps = 0.f, pd = 0.f;
        #pragma unroll
        for (int t = 0; t < 4; ++t) {
            ps = fmaf(acc[j][t], a_s[t], ps);
            pd = fmaf(acc[j][t], a_d[t], pd);
        }
        ps += __shfl_xor(ps, 1, 64);
        pd += __shfl_xor(pd, 1, 64);
        if (n < N) {
            ushort4 hb;
            hb.x = f2bf(acc[j][0]); hb.y = f2bf(acc[j][1]);
            hb.z = f2bf(acc[j][2]); hb.w = f2bf(acc[j][3]);
            *(ushort4*)&h1b[(size_t)n * 64 + 4 * c] = hb;
            if ((c & 1) == 0) {
                als[n * 8 + (c >> 1)] = ps;
                ald[n * 8 + (c >> 1)] = pd;
            }
        }
    }
}

// ---------- atomic-free CSR build (P1..P4, passed full protocol R5/R6/R7) ----------

__global__ __launch_bounds__(256) void p1(const int* __restrict__ ei, int E, int N,
        int* __restrict__ T, int NB, int NC)
{
    extern __shared__ int hist[];
    int tid = threadIdx.x;
    for (int b = tid; b < NB; b += 256) hist[b] = 0;
    __syncthreads();
    int base = blockIdx.x * CHUNK;
    for (int i = tid; i < CHUNK; i += 256) {
        int e = base + i;
        if (e >= E) break;
        int d = ei[E + e];
        if ((unsigned)d < (unsigned)N) atomicAdd(&hist[d >> 8], 1);
    }
    __syncthreads();
    for (int b = tid; b < NB; b += 256) T[b * NC + blockIdx.x] = hist[b];
}

__global__ __launch_bounds__(256) void p2a(int* __restrict__ T,
        int* __restrict__ total, int NB, int NC)
{
    int wave = threadIdx.x >> 6, lane = threadIdx.x & 63;
    int b = blockIdx.x * 4 + wave;
    if (b >= NB) return;
    int run = 0;
    for (int j0 = 0; j0 < NC; j0 += 64) {
        int j = j0 + lane;
        int orig = (j < NC) ? T[b * NC + j] : 0;
        int v = orig;
        #pragma unroll
        for (int off = 1; off < 64; off <<= 1) {
            int t = __shfl_up(v, off, 64);
            if (lane >= off) v += t;
        }
        if (j < NC) T[b * NC + j] = run + v - orig;
        run += __shfl(v, 63, 64);
    }
    if (lane == 0) total[b] = run;
}

__global__ __launch_bounds__(512) void p2b(const int* __restrict__ total,
        int* __restrict__ bstart, int nb)
{
    __shared__ int s[512];
    int tid = threadIdx.x;
    int run = 0;
    for (int base = 0; base < nb; base += 512) {
        int i = base + tid;
        int orig = (i < nb) ? total[i] : 0;
        s[tid] = orig;
        __syncthreads();
        #pragma unroll
        for (int off = 1; off < 512; off <<= 1) {
            int t = (tid >= off) ? s[tid - off] : 0;
            __syncthreads();
            s[tid] += t;
            __syncthreads();
        }
        if (i < nb) bstart[i] = run + s[tid] - orig;
        int tot = s[511];
        __syncthreads();
        run += tot;
    }
    if (tid == 0) bstart[nb] = run;
}

__global__ __launch_bounds__(256) void p3(const int* __restrict__ ei, int E, int N,
        const int* __restrict__ T, const int* __restrict__ bstart,
        unsigned* __restrict__ tmp, int NB, int NC)
{
    extern __shared__ int cur[];
    int tid = threadIdx.x;
    int j = blockIdx.x;
    for (int b = tid; b < NB; b += 256) cur[b] = bstart[b] + T[b * NC + j];
    __syncthreads();
    int base = j * CHUNK;
    for (int i = tid; i < CHUNK; i += 256) {
        int e = base + i;
        if (e >= E) break;
        int d = ei[E + e];
        if ((unsigned)d >= (unsigned)N) continue;
        int s = ei[e];
        if ((unsigned)s >= (unsigned)N) s = 0;
        int pos = atomicAdd(&cur[d >> 8], 1);
        if ((unsigned)pos < (unsigned)E)
            tmp[pos] = (unsigned)s | ((unsigned)(d & 255) << 24);
    }
}

__global__ __launch_bounds__(256) void p4(const unsigned* __restrict__ tmp,
        const int* __restrict__ bstart,
        int* __restrict__ cnt, int* __restrict__ rowptr, int* __restrict__ csr,
        int N, int E)
{
    __shared__ int hist[256];
    __shared__ int ssc[256];
    __shared__ int cur[256];
    int tid = threadIdx.x;
    int b = blockIdx.x;
    int s0 = bstart[b], s1 = bstart[b + 1];
    if (s0 < 0) s0 = 0; if (s0 > E) s0 = E;
    if (s1 < s0) s1 = s0; if (s1 > E) s1 = E;

    hist[tid] = 0;
    __syncthreads();
    for (int i = s0 + tid; i < s1; i += 256)
        atomicAdd(&hist[tmp[i] >> 24], 1);
    __syncthreads();

    int h = hist[tid];
    ssc[tid] = h;
    __syncthreads();
    #pragma unroll
    for (int off = 1; off < 256; off <<= 1) {
        int t = (tid >= off) ? ssc[tid - off] : 0;
        __syncthreads();
        ssc[tid] += t;
        __syncthreads();
    }
    int excl = ssc[tid] - h;
    int node = b * 256 + tid;
    if (node < N) {
        cnt[node] = h;
        rowptr[node] = s0 + excl;
    }
    cur[tid] = s0 + excl;
    __syncthreads();

    for (int i = s0 + tid; i < s1; i += 256) {
        unsigned v = tmp[i];
        int pos = atomicAdd(&cur[v >> 24], 1);
        if ((unsigned)pos < (unsigned)E) csr[pos] = (int)(v & 0xFFFFFFu);
    }
}

// ---------- fallback atomic build (proven R3/R4) ----------

__global__ __launch_bounds__(256) void kh(const int* __restrict__ ei, int E, int N,
                                          int* __restrict__ cnt)
{
    int e = blockIdx.x * 256 + threadIdx.x;
    if (e >= E) return;
    int d = ei[E + e];
    if ((unsigned)d < (unsigned)N) atomicAdd(&cnt[d], 1);
}

__global__ __launch_bounds__(256) void ka(const int* __restrict__ cnt,
        int* __restrict__ rowptr, int* __restrict__ cursor,
        int* __restrict__ gtotal, int N)
{
    __shared__ int s[256];
    __shared__ int base;
    int tid = threadIdx.x;
    int g = blockIdx.x * 256 + tid;
    int v = (g < N) ? cnt[g] : 0;
    s[tid] = v;
    __syncthreads();
    #pragma unroll
    for (int off = 1; off < 256; off <<= 1) {
        int t = (tid >= off) ? s[tid - off] : 0;
        __syncthreads();
        s[tid] += t;
        __syncthreads();
    }
    if (tid == 255) base = atomicAdd(gtotal, s[255]);
    __syncthreads();
    if (g < N) {
        int r = base + s[tid] - v;
        rowptr[g] = r;
        cursor[g] = r;
    }
}

__global__ __launch_bounds__(256) void kc(const int* __restrict__ ei, int E, int N,
        int* __restrict__ cursor, int* __restrict__ csr)
{
    int e = blockIdx.x * 256 + threadIdx.x;
    if (e >= E) return;
    int s = ei[e];
    int d = ei[E + e];
    if ((unsigned)d >= (unsigned)N) return;
    int p = atomicAdd(&cursor[d], 1);
    if ((unsigned)p < (unsigned)E) csr[p] = s;
}

// ---------- G1 v6: two-phase LDS-staged weights ----------
// One wave per dst node (4/block). Per 64-edge chunk:
//  Phase A: lane owns edge `lane`: loads als[src] (2x float4), computes all 8
//           head weights once, accumulates per-lane den partials in registers,
//           stores w (stride-65 pad) and src<<5 to per-wave LDS.
//  Phase B: parity halves (s=lane>>5) each take one edge per step; lane cp
//           (col pair) does 2 ds_read_b32 (w, soff) + 1 dword h1 load + 2 fma.
// Each wave touches only its own LDS slice; syncthreads are block-uniform
// via cmax. Global writes: h2a[n]/ald2[n] only (guarded).
__global__ __launch_bounds__(256) void g1(const int* __restrict__ csr,
        const int* __restrict__ rowptr, const int* __restrict__ cnt,
        const unsigned short* __restrict__ h1b, const float* __restrict__ als,
        const float* __restrict__ ald,
        const float* __restrict__ b1, const float* __restrict__ W2,
        const float* __restrict__ a_src2, const float* __restrict__ a_dst2,
        float2* __restrict__ h2a, float* __restrict__ ald2, int N, int E)
{
    __shared__ float wl[4][8 * 65];     // [wave][head*65 + edge]
    __shared__ int   sl[4][64];         // [wave][edge] = src<<5
    __shared__ int   csh[4];

    const int wave = threadIdx.x >> 6, lane = threadIdx.x & 63;
    const int n = blockIdx.x * 4 + wave;
    const bool active = (n < N);
    const int n2 = active ? n : 0;

    const int s = lane >> 5;
    const int cp = lane & 31;
    const int hp = cp >> 2;

    const unsigned* h1w = (const unsigned*)h1b;
    const float4* als4 = (const float4*)als;
    const float4* ald4 = (const float4*)ald;

    float4 d0 = ald4[n2 * 2], d1 = ald4[n2 * 2 + 1];
    float aldv[8] = {d0.x, d0.y, d0.z, d0.w, d1.x, d1.y, d1.z, d1.w};

    float denv[8];
    #pragma unroll
    for (int i = 0; i < 8; ++i) denv[i] = 0.f;
    float acc0 = 0.f, acc1 = 0.f;

    int start = active ? rowptr[n2] : 0;
    int c = active ? cnt[n2] : 0;
    if ((unsigned)start >= (unsigned)E) { start = 0; c = 0; }
    if (c < 0) c = 0;
    if (start + c > E) c = E - start;

    if (lane == 0) csh[wave] = c;
    __syncthreads();
    int cmax = max(max(csh[0], csh[1]), max(csh[2], csh[3]));

    float* wlw = wl[wave];
    int* slw = sl[wave];

    for (int cbase = 0; cbase < cmax; cbase += 64) {
        int rem = c - cbase;
        if (rem > 64) rem = 64;
        if (rem < 0) rem = 0;

        // ---- phase A ----
        int esrc = 0;
        if (lane < rem) {
            int t = csr[start + cbase + lane];
            if ((unsigned)t < (unsigned)N) esrc = t;
        }
        float4 a0 = als4[esrc * 2], a1 = als4[esrc * 2 + 1];
        float wv[8];
        wv[0] = __expf(lrelu(a0.x + aldv[0]));
        wv[1] = __expf(lrelu(a0.y + aldv[1]));
        wv[2] = __expf(lrelu(a0.z + aldv[2]));
        wv[3] = __expf(lrelu(a0.w + aldv[3]));
        wv[4] = __expf(lrelu(a1.x + aldv[4]));
        wv[5] = __expf(lrelu(a1.y + aldv[5]));
        wv[6] = __expf(lrelu(a1.z + aldv[6]));
        wv[7] = __expf(lrelu(a1.w + aldv[7]));
        if (lane >= rem) {
            #pragma unroll
            for (int i = 0; i < 8; ++i) wv[i] = 0.f;
        }
        #pragma unroll
        for (int i = 0; i < 8; ++i) {
            denv[i] += wv[i];
            wlw[i * 65 + lane] = wv[i];
        }
        slw[lane] = esrc << 5;
        __syncthreads();

        // ---- phase B ----
        int steps = (rem + 1) >> 1;
        #pragma unroll 4
        for (int i = 0; i < steps; ++i) {
            int ge = 2 * i + s;
            float w = wlw[hp * 65 + ge];
            int soff = slw[ge];
            unsigned u = h1w[soff + cp];
            acc0 = fmaf(w, __uint_as_float(u << 16), acc0);
            acc1 = fmaf(w, __uint_as_float(u & 0xffff0000u), acc1);
        }
        __syncthreads();
    }

    // reduce den partials across all 64 lanes (element-wise tree)
    #pragma unroll
    for (int off = 1; off < 64; off <<= 1) {
        #pragma unroll
        for (int i = 0; i < 8; ++i) denv[i] += __shfl_xor(denv[i], off, 64);
    }
    float q0 = (hp & 1) ? denv[1] : denv[0];
    float q1 = (hp & 1) ? denv[3] : denv[2];
    float q2 = (hp & 1) ? denv[5] : denv[4];
    float q3 = (hp & 1) ? denv[7] : denv[6];
    float r0 = (hp & 2) ? q1 : q0;
    float r1 = (hp & 2) ? q3 : q2;
    float den = (hp & 4) ? r1 : r0;

    // combine the two edge-parity halves
    acc0 += __shfl_xor(acc0, 32, 64);
    acc1 += __shfl_xor(acc1, 32, 64);

    // self-loop
    float wsf = __expf(lrelu(als[n2 * 8 + hp] + aldv[hp]));
    unsigned un = h1w[(n2 << 5) + cp];
    den += wsf;
    acc0 = fmaf(wsf, __uint_as_float(un << 16), acc0);
    acc1 = fmaf(wsf, __uint_as_float(un & 0xffff0000u), acc1);

    // epilogue: normalize, +b1, ReLU, dot W2, reduce across wave
    float2 bb = *(const float2*)&b1[2 * cp];
    float2 w2 = *(const float2*)&W2[2 * cp];
    float v0 = fmaxf(acc0 / den + bb.x, 0.f);
    float v1 = fmaxf(acc1 / den + bb.y, 0.f);
    float t = fmaf(v0, w2.x, v1 * w2.y);
    #pragma unroll
    for (int off = 1; off < 32; off <<= 1) t += __shfl_xor(t, off, 64);
    if (active && lane == 0) {
        float2 p;
        p.x = t;
        p.y = t * a_src2[0];
        h2a[n] = p;
        ald2[n] = t * a_dst2[0];
    }
}

// G2: fused layer-2 gather + final normalize (proven R4-R7).
__global__ __launch_bounds__(256) void g2(const int* __restrict__ csr,
        const int* __restrict__ rowptr, const int* __restrict__ cnt,
        const float2* __restrict__ h2a, const float* __restrict__ ald2,
        const float* __restrict__ b2, float* __restrict__ out, int N, int E)
{
    int sub = threadIdx.x >> 5;
    int l32 = threadIdx.x & 31;
    int n = blockIdx.x * 8 + sub;
    if (n >= N) return;

    float ad = ald2[n];
    int start = rowptr[n];
    int c = cnt[n];
    if ((unsigned)start >= (unsigned)E) { start = 0; c = 0; }
    if (c < 0) c = 0;
    if (start + c > E) c = E - start;

    float den = 0.f, acc = 0.f;
    for (int i = l32; i < c; i += 32) {
        int src = csr[start + i];
        if ((unsigned)src >= (unsigned)N) src = 0;
        float2 p = h2a[src];
        float w = __expf(lrelu(p.y + ad));
        den += w;
        acc = fmaf(w, p.x, acc);
    }
    #pragma unroll
    for (int off = 1; off < 32; off <<= 1) {
        den += __shfl_xor(den, off, 32);
        acc += __shfl_xor(acc, off, 32);
    }
    if (l32 == 0) {
        float2 p = h2a[n];
        float w0 = __expf(lrelu(p.y + ad));
        out[n] = (acc + w0 * p.x) / (den + w0) + b2[0];
    }
}

extern "C" void kernel_launch(void* const* d_in, const int* in_sizes, int n_in,
                              void* d_out, int out_size, void* d_ws, size_t ws_size,
                              hipStream_t stream)
{
    const float* x   = (const float*)d_in[0];
    const float* W1  = (const float*)d_in[1];
    const float* as1 = (const float*)d_in[2];
    const float* ad1 = (const float*)d_in[3];
    const float* b1  = (const float*)d_in[4];
    const float* W2  = (const float*)d_in[5];
    const float* as2 = (const float*)d_in[6];
    const float* ad2 = (const float*)d_in[7];
    const float* b2  = (const float*)d_in[8];
    const int*   ei  = (const int*)d_in[9];

    int N = in_sizes[0] / 128;
    int E = in_sizes[9] / 2;
    int NB = (N + 255) >> 8;
    int NC = (E + CHUNK - 1) / CHUNK;

    char* wsb = (char*)d_ws;
    size_t off = 0;
    auto alloc = [&](size_t bytes) -> char* {
        char* p = wsb + off;
        off = (off + bytes + 255) & ~(size_t)255;
        return p;
    };

    unsigned short* h1b = (unsigned short*)alloc((size_t)N * 64 * 2);
    float* als    = (float*)alloc((size_t)N * 8 * 4);
    float* ald    = (float*)alloc((size_t)N * 8 * 4);
    float2* h2a   = (float2*)alloc((size_t)N * 8);
    float* ald2   = (float*)alloc((size_t)N * 4);
    int* cnt      = (int*)alloc((size_t)N * 4);
    int* rowptr   = (int*)alloc((size_t)N * 4);
    int* csr      = (int*)alloc((size_t)E * 4);
    size_t common = off;

    int* T        = (int*)alloc((size_t)NB * NC * 4);
    int* total    = (int*)alloc((size_t)NB * 4);
    int* bstart   = (int*)alloc((size_t)(NB + 1) * 4);
    unsigned* tmp = (unsigned*)alloc((size_t)E * 4);
    size_t need_new = off;

    k1<<<(N + 63) / 64, 256, 0, stream>>>(x, W1, as1, ad1, h1b, als, ald, N);

    if (ws_size >= need_new && NB <= 512) {
        size_t lds = (size_t)NB * 4;
        p1<<<NC, 256, lds, stream>>>(ei, E, N, T, NB, NC);
        p2a<<<(NB + 3) / 4, 256, 0, stream>>>(T, total, NB, NC);
        p2b<<<1, 512, 0, stream>>>(total, bstart, NB);
        p3<<<NC, 256, lds, stream>>>(ei, E, N, T, bstart, tmp, NB, NC);
        p4<<<NB, 256, 0, stream>>>(tmp, bstart, cnt, rowptr, csr, N, E);
    } else {
        off = common;
        int* gtotal = (int*)alloc(32);
        int* cursor = (int*)alloc((size_t)N * 4);
        hipMemsetAsync(cnt, 0, (size_t)N * sizeof(int), stream);
        hipMemsetAsync(gtotal, 0, 32, stream);
        kh<<<(E + 255) / 256, 256, 0, stream>>>(ei, E, N, cnt);
        ka<<<(N + 255) / 256, 256, 0, stream>>>(cnt, rowptr, cursor, gtotal, N);
        kc<<<(E + 255) / 256, 256, 0, stream>>>(ei, E, N, cursor, csr);
    }

    g1<<<(N + 3) / 4, 256, 0, stream>>>(csr, rowptr, cnt, h1b, als, ald,
                                        b1, W2, as2, ad2, h2a, ald2, N, E);
    g2<<<(N + 7) / 8, 256, 0, stream>>>(csr, rowptr, cnt, h2a, ald2, b2,
                                        (float*)d_out, N, E);
}